// Round 3
// baseline (620.220 us; speedup 1.0000x reference)
//
#include <hip/hip_runtime.h>
#include <hip/hip_bf16.h>

// DeepseekV4 shared expert: int8 dynamic-quant SwiGLU MLP.
// T=8192 tokens, H=4096 hidden, I=2048 intermediate.
// R3: all int8 operands stored in MFMA-fragment-linear packed layout
// (micro-tile = 32 rows x 64 k = 2048B; addr = (row>>5)*K*32 + (k>>6)*2048
//  + ((k>>4)&3)*512 + (row&31)*16 + (k&15)). Staging global->LDS is
// contiguous->contiguous; ds_read_b128 is lane-linear => conflict-free.

typedef __attribute__((ext_vector_type(4))) int i32x4;
typedef __attribute__((ext_vector_type(16))) int i32x16;

__device__ __forceinline__ void async16(void* lds, const void* g) {
  __builtin_amdgcn_global_load_lds(
      (const __attribute__((address_space(1))) void*)g,
      (__attribute__((address_space(3))) void*)lds, 16, 0, 0);
}

__device__ __forceinline__ i32x16 mfma32(i32x4 a, i32x4 b, i32x16 c) {
  return __builtin_amdgcn_mfma_i32_32x32x32_i8(a, b, c, 0, 0, 0);
}

__device__ __forceinline__ float bf16_rne_f(float f) {
  unsigned u = __float_as_uint(f);
  u += 0x7fffu + ((u >> 16) & 1u);
  return __uint_as_float(u & 0xffff0000u);
}
__device__ __forceinline__ unsigned short bf16_bits(float f) {
  unsigned u = __float_as_uint(f);
  u += 0x7fffu + ((u >> 16) & 1u);
  return (unsigned short)(u >> 16);
}
__device__ __forceinline__ float bf16_to_f(unsigned short h) {
  return __uint_as_float(((unsigned)h) << 16);
}

// ---------------- weight fp32 (int8-valued) -> packed int8 ----------------
// block: 32 rows; thread (m=tid&31, sub=tid>>5) loops chunks kc=sub+8*i.
// Reads 64B contiguous per thread; writes 512B contiguous per 32-lane group.
__global__ __launch_bounds__(256) void wconv_kernel(
    const float* __restrict__ w0, const float* __restrict__ w1,
    const float* __restrict__ w2, signed char* __restrict__ q0,
    signed char* __restrict__ q1, signed char* __restrict__ q2,
    int H, int I) {
  const int wid = blockIdx.y;
  const float* w = (wid == 0) ? w0 : (wid == 1) ? w1 : w2;
  signed char* q = (wid == 0) ? q0 : (wid == 1) ? q1 : q2;
  const int K = (wid == 2) ? I : H;         // inner dim
  const int R = (wid == 2) ? H : I;         // rows
  const int rt = blockIdx.x;                // row tile (32 rows)
  if (rt * 32 >= R) return;
  const int m = threadIdx.x & 31, sub = threadIdx.x >> 5;
  const int row = rt * 32 + m;
  const int nkc = K >> 4;                   // 16-elem chunks per row
  const size_t outTile = (size_t)rt * K * 32 + (size_t)m * 16;
  for (int kc = sub; kc < nkc; kc += 8) {
    const float* src = w + (size_t)row * K + kc * 16;
    signed char c[16] __attribute__((aligned(16)));
#pragma unroll
    for (int v = 0; v < 4; ++v) {
      float4 f = *(const float4*)(src + v * 4);
      c[v * 4 + 0] = (signed char)(int)rintf(f.x);
      c[v * 4 + 1] = (signed char)(int)rintf(f.y);
      c[v * 4 + 2] = (signed char)(int)rintf(f.z);
      c[v * 4 + 3] = (signed char)(int)rintf(f.w);
    }
    *(i32x4*)(q + outTile + (kc >> 2) * 2048 + (kc & 3) * 512) =
        *(const i32x4*)c;
  }
}

// ---------------- per-token quant of x -> packed qg/qu ----------------
__global__ __launch_bounds__(256) void quant_x_kernel(
    const float* __restrict__ x, const float* __restrict__ invg,
    const float* __restrict__ invu, signed char* __restrict__ qg,
    signed char* __restrict__ qu, float* __restrict__ sg,
    float* __restrict__ su, int H) {
  const int t = blockIdx.x, tid = threadIdx.x;
  const float* xr = x + (size_t)t * H;
  const int c0 = tid * 16;  // chunk kc = tid (H/16 == 256 == blockDim)
  float xg[16], xu[16];
  float mg = 0.f, mu = 0.f;
#pragma unroll
  for (int v = 0; v < 4; ++v) {
    float4 f = *(const float4*)(xr + c0 + v * 4);
    float4 ig = *(const float4*)(invg + c0 + v * 4);
    float4 iu = *(const float4*)(invu + c0 + v * 4);
    float b0 = bf16_rne_f(f.x), b1 = bf16_rne_f(f.y);
    float b2 = bf16_rne_f(f.z), b3 = bf16_rne_f(f.w);
    xg[v * 4 + 0] = b0 * ig.x; xg[v * 4 + 1] = b1 * ig.y;
    xg[v * 4 + 2] = b2 * ig.z; xg[v * 4 + 3] = b3 * ig.w;
    xu[v * 4 + 0] = b0 * iu.x; xu[v * 4 + 1] = b1 * iu.y;
    xu[v * 4 + 2] = b2 * iu.z; xu[v * 4 + 3] = b3 * iu.w;
#pragma unroll
    for (int j = 0; j < 4; ++j) {
      mg = fmaxf(mg, fabsf(xg[v * 4 + j]));
      mu = fmaxf(mu, fabsf(xu[v * 4 + j]));
    }
  }
#pragma unroll
  for (int off = 32; off > 0; off >>= 1) {
    mg = fmaxf(mg, __shfl_xor(mg, off));
    mu = fmaxf(mu, __shfl_xor(mu, off));
  }
  __shared__ float smg[4], smu[4];
  if ((tid & 63) == 0) { smg[tid >> 6] = mg; smu[tid >> 6] = mu; }
  __syncthreads();
  mg = fmaxf(fmaxf(smg[0], smg[1]), fmaxf(smg[2], smg[3]));
  mu = fmaxf(fmaxf(smu[0], smu[1]), fmaxf(smu[2], smu[3]));
  const float scg = fmaxf(mg / 127.0f, 1e-8f);
  const float scu = fmaxf(mu / 127.0f, 1e-8f);
  const float rg = 1.0f / scg, ru = 1.0f / scu;
  signed char og[16] __attribute__((aligned(16)));
  signed char ou[16] __attribute__((aligned(16)));
#pragma unroll
  for (int j = 0; j < 16; ++j) {
    og[j] = (signed char)(int)fminf(fmaxf(rintf(xg[j] * rg), -127.f), 127.f);
    ou[j] = (signed char)(int)fminf(fmaxf(rintf(xu[j] * ru), -127.f), 127.f);
  }
  // packed: chunk kc = tid of row t
  const size_t off8 = (size_t)(t >> 5) * H * 32 + (tid >> 2) * 2048 +
                      (tid & 3) * 512 + (t & 31) * 16;
  *(i32x4*)(qg + off8) = *(const i32x4*)og;
  *(i32x4*)(qu + off8) = *(const i32x4*)ou;
  if (tid == 0) { sg[t] = scg; su[t] = scu; }
}

// ---------------- fused gate+up GEMM + SwiGLU -> inter (row-major bf16) ----
__global__ __launch_bounds__(256, 2) void gemm1_kernel(
    const signed char* __restrict__ qg, const signed char* __restrict__ qu,
    const float* __restrict__ sg, const float* __restrict__ su,
    const signed char* __restrict__ wg, const signed char* __restrict__ wu,
    const float* __restrict__ swg, const float* __restrict__ swu,
    unsigned short* __restrict__ inter, int H, int I) {
  __shared__ signed char Ag[128 * 64] __attribute__((aligned(16)));
  __shared__ signed char Au[128 * 64] __attribute__((aligned(16)));
  __shared__ signed char Bg[128 * 64] __attribute__((aligned(16)));
  __shared__ signed char Bu[128 * 64] __attribute__((aligned(16)));
  const int tid = threadIdx.x;
  const int lane = tid & 63, wave = tid >> 6;
  const int row0 = blockIdx.x * 128, col0 = blockIdx.y * 128;
  const int ah = wave & 1, bh = wave >> 1;  // 64-row / 64-col halves
  const int m = lane & 31, h = lane >> 5;

  const size_t rts = (size_t)H * 32;  // row-tile (32 rows) stride, bytes
  const int o = tid & 127, mt0 = tid >> 7;
  const size_t aoff = (size_t)(row0 >> 5) * rts + (size_t)mt0 * rts + o * 16;
  const size_t boff = (size_t)(col0 >> 5) * rts + (size_t)mt0 * rts + o * 16;
  const signed char* pAg = qg + aoff;
  const signed char* pAu = qu + aoff;
  const signed char* pBg = wg + boff;
  const signed char* pBu = wu + boff;
  const int lds0 = tid * 16, lds1 = tid * 16 + 4096;
  const size_t skip = rts * 2;  // micro-tiles mt0 and mt0+2

  i32x16 accG[2][2], accU[2][2];
#pragma unroll
  for (int i = 0; i < 2; ++i)
#pragma unroll
    for (int j = 0; j < 2; ++j) {
      accG[i][j] = (i32x16)(0);
      accU[i][j] = (i32x16)(0);
    }

  const signed char* aBaseG = &Ag[ah * 4096 + lane * 16];
  const signed char* aBaseU = &Au[ah * 4096 + lane * 16];
  const signed char* bBaseG = &Bg[bh * 4096 + lane * 16];
  const signed char* bBaseU = &Bu[bh * 4096 + lane * 16];

  for (int kt = 0; kt < (H >> 6); ++kt) {
    __syncthreads();
    async16(&Ag[lds0], pAg);
    async16(&Ag[lds1], pAg + skip);
    async16(&Au[lds0], pAu);
    async16(&Au[lds1], pAu + skip);
    async16(&Bg[lds0], pBg);
    async16(&Bg[lds1], pBg + skip);
    async16(&Bu[lds0], pBu);
    async16(&Bu[lds1], pBu + skip);
    pAg += 2048; pAu += 2048; pBg += 2048; pBu += 2048;
    __syncthreads();
#pragma unroll
    for (int s = 0; s < 2; ++s) {
      i32x4 aG[2], aU[2], bG[2], bU[2];
#pragma unroll
      for (int i = 0; i < 2; ++i) {
        aG[i] = *(const i32x4*)(aBaseG + i * 2048 + s * 1024);
        aU[i] = *(const i32x4*)(aBaseU + i * 2048 + s * 1024);
        bG[i] = *(const i32x4*)(bBaseG + i * 2048 + s * 1024);
        bU[i] = *(const i32x4*)(bBaseU + i * 2048 + s * 1024);
      }
#pragma unroll
      for (int i = 0; i < 2; ++i)
#pragma unroll
        for (int j = 0; j < 2; ++j) {
          accG[i][j] = mfma32(aG[i], bG[j], accG[i][j]);
          accU[i][j] = mfma32(aU[i], bU[j], accU[i][j]);
        }
    }
  }

  // epilogue: dequant, silu(g)*u, clip +-10, bf16 RNE, store row-major
  float swgc[2], swuc[2];
#pragma unroll
  for (int j = 0; j < 2; ++j) {
    const int c = col0 + bh * 64 + j * 32 + m;
    swgc[j] = swg[c];
    swuc[j] = swu[c];
  }
#pragma unroll
  for (int i = 0; i < 2; ++i) {
#pragma unroll
    for (int reg = 0; reg < 16; ++reg) {
      const int row =
          row0 + ah * 64 + i * 32 + (reg & 3) + 8 * (reg >> 2) + 4 * h;
      const float sgr = sg[row], sur = su[row];
#pragma unroll
      for (int j = 0; j < 2; ++j) {
        const int c = col0 + bh * 64 + j * 32 + m;
        const float g = (float)accG[i][j][reg] * sgr * swgc[j];
        const float u = (float)accU[i][j][reg] * sur * swuc[j];
        const float sig = 1.f / (1.f + __expf(-g));
        float v = (g * sig) * u;
        v = fminf(fmaxf(v, -10.f), 10.f);
        inter[(size_t)row * I + c] = bf16_bits(v);
      }
    }
  }
}

// ---------------- per-token quant of inter -> packed qi ----------------
// block = 2 tokens; thread group (tid>>7) = token, kc = tid&127.
__global__ __launch_bounds__(256) void quant_i_kernel(
    const unsigned short* __restrict__ inter, const float* __restrict__ invi,
    signed char* __restrict__ qi, float* __restrict__ si, int I) {
  const int tid = threadIdx.x;
  const int t = blockIdx.x * 2 + (tid >> 7);
  const int kc = tid & 127;  // I/16 == 128 chunks per token
  const unsigned short* ir = inter + (size_t)t * I + kc * 16;
  uint4 p0 = *(const uint4*)ir;
  uint4 p1 = *(const uint4*)(ir + 8);
  const float* iv = invi + kc * 16;
  float xs[16];
  {
    const unsigned pk[8] = {p0.x, p0.y, p0.z, p0.w, p1.x, p1.y, p1.z, p1.w};
#pragma unroll
    for (int j = 0; j < 8; ++j) {
      xs[j * 2] = bf16_to_f((unsigned short)(pk[j] & 0xffffu)) * iv[j * 2];
      xs[j * 2 + 1] = bf16_to_f((unsigned short)(pk[j] >> 16)) * iv[j * 2 + 1];
    }
  }
  float mx = 0.f;
#pragma unroll
  for (int j = 0; j < 16; ++j) mx = fmaxf(mx, fabsf(xs[j]));
#pragma unroll
  for (int off = 32; off > 0; off >>= 1) mx = fmaxf(mx, __shfl_xor(mx, off));
  __shared__ float sm[4];
  if ((tid & 63) == 0) sm[tid >> 6] = mx;
  __syncthreads();
  mx = (tid >> 7) ? fmaxf(sm[2], sm[3]) : fmaxf(sm[0], sm[1]);
  const float s = fmaxf(mx / 127.0f, 1e-8f);
  const float rs = 1.0f / s;
  signed char oq[16] __attribute__((aligned(16)));
#pragma unroll
  for (int j = 0; j < 16; ++j)
    oq[j] = (signed char)(int)fminf(fmaxf(rintf(xs[j] * rs), -127.f), 127.f);
  const size_t off8 = (size_t)(t >> 5) * I * 32 + (kc >> 2) * 2048 +
                      (kc & 3) * 512 + (t & 31) * 16;
  *(i32x4*)(qi + off8) = *(const i32x4*)oq;
  if (kc == 0) si[t] = s;
}

// ---------------- down GEMM -> out fp32 row-major ----------------
__global__ __launch_bounds__(256, 2) void gemm2_kernel(
    const signed char* __restrict__ qi, const float* __restrict__ si,
    const signed char* __restrict__ wd, const float* __restrict__ swd,
    float* __restrict__ out, int H, int I) {
  __shared__ signed char As[128 * 64] __attribute__((aligned(16)));
  __shared__ signed char Bs[128 * 64] __attribute__((aligned(16)));
  const int tid = threadIdx.x;
  const int lane = tid & 63, wave = tid >> 6;
  const int row0 = blockIdx.x * 128, col0 = blockIdx.y * 128;
  const int ah = wave & 1, bh = wave >> 1;
  const int m = lane & 31, h = lane >> 5;

  const size_t rts = (size_t)I * 32;
  const int o = tid & 127, mt0 = tid >> 7;
  const signed char* pA =
      qi + (size_t)(row0 >> 5) * rts + (size_t)mt0 * rts + o * 16;
  const signed char* pB =
      wd + (size_t)(col0 >> 5) * rts + (size_t)mt0 * rts + o * 16;
  const int lds0 = tid * 16, lds1 = tid * 16 + 4096;
  const size_t skip = rts * 2;

  i32x16 acc[2][2];
#pragma unroll
  for (int i = 0; i < 2; ++i)
#pragma unroll
    for (int j = 0; j < 2; ++j) acc[i][j] = (i32x16)(0);

  const signed char* aBase = &As[ah * 4096 + lane * 16];
  const signed char* bBase = &Bs[bh * 4096 + lane * 16];

  for (int kt = 0; kt < (I >> 6); ++kt) {
    __syncthreads();
    async16(&As[lds0], pA);
    async16(&As[lds1], pA + skip);
    async16(&Bs[lds0], pB);
    async16(&Bs[lds1], pB + skip);
    pA += 2048; pB += 2048;
    __syncthreads();
#pragma unroll
    for (int s = 0; s < 2; ++s) {
      i32x4 a[2], b[2];
#pragma unroll
      for (int i = 0; i < 2; ++i) {
        a[i] = *(const i32x4*)(aBase + i * 2048 + s * 1024);
        b[i] = *(const i32x4*)(bBase + i * 2048 + s * 1024);
      }
#pragma unroll
      for (int i = 0; i < 2; ++i)
#pragma unroll
        for (int j = 0; j < 2; ++j) acc[i][j] = mfma32(a[i], b[j], acc[i][j]);
    }
  }

  float swc[2];
#pragma unroll
  for (int j = 0; j < 2; ++j) swc[j] = swd[col0 + bh * 64 + j * 32 + m];
#pragma unroll
  for (int i = 0; i < 2; ++i) {
#pragma unroll
    for (int reg = 0; reg < 16; ++reg) {
      const int row =
          row0 + ah * 64 + i * 32 + (reg & 3) + 8 * (reg >> 2) + 4 * h;
      const float sir = si[row];
#pragma unroll
      for (int j = 0; j < 2; ++j) {
        const int c = col0 + bh * 64 + j * 32 + m;
        out[(size_t)row * H + c] = (float)acc[i][j][reg] * sir * swc[j];
      }
    }
  }
}

extern "C" void kernel_launch(void* const* d_in, const int* in_sizes, int n_in,
                              void* d_out, int out_size, void* d_ws,
                              size_t ws_size, hipStream_t stream) {
  const float* x = (const float*)d_in[0];
  const float* w_gate = (const float*)d_in[1];
  const float* s_wgate = (const float*)d_in[2];
  const float* w_up = (const float*)d_in[3];
  const float* s_wup = (const float*)d_in[4];
  const float* w_down = (const float*)d_in[5];
  const float* s_wdown = (const float*)d_in[6];
  const float* inv_gate = (const float*)d_in[7];
  const float* inv_up = (const float*)d_in[8];
  const float* inv_inter = (const float*)d_in[9];
  float* out = (float*)d_out;

  const int H = in_sizes[6];          // 4096
  const int I = in_sizes[2];          // 2048
  const int T = in_sizes[0] / H;      // 8192

  char* ws = (char*)d_ws;
  size_t off = 0;
  signed char* wqg = (signed char*)(ws + off); off += (size_t)I * H;
  signed char* wqu = (signed char*)(ws + off); off += (size_t)I * H;
  signed char* wqd = (signed char*)(ws + off); off += (size_t)H * I;
  signed char* qg  = (signed char*)(ws + off); off += (size_t)T * H;
  signed char* qu  = (signed char*)(ws + off); off += (size_t)T * H;
  unsigned short* inter = (unsigned short*)(ws + off); off += (size_t)T * I * 2;
  float* sg = (float*)(ws + off); off += (size_t)T * 4;
  float* su = (float*)(ws + off); off += (size_t)T * 4;
  float* si = (float*)(ws + off); off += (size_t)T * 4;
  signed char* qi = qg;  // qg dead after gemm1

  dim3 gw(H / 32, 3);  // max row-tiles (w_down: H rows); gate/up skip extras
  wconv_kernel<<<gw, 256, 0, stream>>>(w_gate, w_up, w_down, wqg, wqu, wqd,
                                       H, I);

  quant_x_kernel<<<T, 256, 0, stream>>>(x, inv_gate, inv_up, qg, qu, sg, su, H);

  dim3 g1(T / 128, I / 128);
  gemm1_kernel<<<g1, 256, 0, stream>>>(qg, qu, sg, su, wqg, wqu, s_wgate,
                                       s_wup, inter, H, I);

  quant_i_kernel<<<T / 2, 256, 0, stream>>>(inter, inv_inter, qi, si, I);

  dim3 g2(T / 128, H / 128);
  gemm2_kernel<<<g2, 256, 0, stream>>>(qi, si, wqd, s_wdown, out, H, I);
}